// Round 17
// baseline (191.216 us; speedup 1.0000x reference)
//
#include <hip/hip_runtime.h>
#include <hip/hip_cooperative_groups.h>
namespace cg = cooperative_groups;

#define NN 100000
#define NE 800000
#define BSH 9                 // 512 nodes per bucket
#define BSZ (1 << BSH)
#define NBUK ((NN + BSZ - 1) / BSZ)    // 196
#define NCHUNK 196            // edge chunks of 4096
#define CAPB 64               // per-(chunk,bucket) capacity (mean 21, 9 sigma)
#define CAP_C 7168            // csr bucket capacity (x8-padded spans)
#define NTILE 782             // 128-node tiles
#define NHTILE 391            // 256-node head tiles

typedef _Float16 half8 __attribute__((ext_vector_type(8)));
typedef float f32x4 __attribute__((ext_vector_type(4)));

// ---------------- setup: weights + cvec + dummy rows + x->f16 + edge binning ----------------
__global__ __launch_bounds__(256) void k_setup(
    const float* __restrict__ W1r, const float* __restrict__ W1o,
    const float* __restrict__ W2r, const float* __restrict__ W2o,
    const float* __restrict__ W3, const float* __restrict__ b3,
    const float* __restrict__ Wlin, const float* __restrict__ blin,
    const float* __restrict__ x, const int* __restrict__ ei,
    _Float16* __restrict__ W12, _Float16* __restrict__ W34h,
    float* __restrict__ cvec,
    _Float16* __restrict__ xh, _Float16* __restrict__ Ah, _Float16* __restrict__ P,
    int* __restrict__ cnt2, int* __restrict__ ebuf2)
{
  const int m = blockIdx.x, tid = threadIdx.x;

  if (m >= 3129) {
    __shared__ int curs[256];
    const int c = m - 3129;
    curs[tid] = 0;
    __syncthreads();
    const int e0 = c * 4096;
    int pk[16], bk[16];
#pragma unroll
    for (int i = 0; i < 16; ++i) {
      int e = e0 + i * 256 + tid;
      if (e < NE) {
        int src = ei[e];
        int dst = ei[NE + e];
        bk[i] = dst >> BSH;
        pk[i] = src | ((dst & (BSZ - 1)) << 17);
      } else bk[i] = -1;
    }
#pragma unroll
    for (int i = 0; i < 16; ++i) {
      if (bk[i] >= 0) {
        int slot = atomicAdd(&curs[bk[i]], 1);            // LDS atomic only
        ebuf2[(c * NBUK + bk[i]) * CAPB + slot] = pk[i];
      }
    }
    __syncthreads();
    if (tid < NBUK) cnt2[c * NBUK + tid] = curs[tid];
    return;
  }

  if (m >= 4) {
    int idx = (m - 4) * 256 + tid;              // 0..799999 exact
    const float4* p4 = (const float4*)(x + idx * 8);
    float4 a = p4[0], b = p4[1];
    half8 h;
    h[0] = (_Float16)a.x; h[1] = (_Float16)a.y; h[2] = (_Float16)a.z; h[3] = (_Float16)a.w;
    h[4] = (_Float16)b.x; h[5] = (_Float16)b.y; h[6] = (_Float16)b.z; h[7] = (_Float16)b.w;
    *(half8*)(xh + idx * 8) = h;
    return;
  }

  if (m < 2) {
    const float* Wr = m ? W2r : W1r;
    const float* Wo = m ? W2o : W1o;
    _Float16* dst = W12 + m * 8192;
    for (int idx = tid; idx < 8192; idx += 256) {
      int n = idx >> 7, k = idx & 127;
      float v = (k < 64) ? Wr[k * 64 + n] : Wo[(k - 64) * 64 + n];
      dst[idx] = (_Float16)v;
    }
  } else if (m == 2) {
    for (int idx = tid; idx < 1024; idx += 256) {
      int c = idx >> 6, k = idx & 63;
      float s = 0.f;
      if (c < 10)
        for (int j = 0; j < 64; ++j) s = fmaf(W3[k * 64 + j], Wlin[j * 10 + c], s);
      W34h[idx] = (_Float16)s;
    }
    if (tid < 10) {
      float s = blin[tid];
      for (int j = 0; j < 64; ++j) s = fmaf(b3[j], Wlin[j * 10 + tid], s);
      cvec[tid] = s;
    }
  } else {  // m == 3: dummy zero rows
    if (tid < 64) {
      xh[NN * 64 + tid] = (_Float16)0.f;
      Ah[NN * 64 + tid] = (_Float16)0.f;
    }
    if (tid < 16) P[NN * 16 + tid] = (_Float16)0.f;
  }
}

// ---------------- CSR build: one block per bucket ----------------
__global__ __launch_bounds__(256) void k_csr2(const int* __restrict__ cnt2,
    const int* __restrict__ ebuf2, int2* __restrict__ rp2, int* __restrict__ csr,
    float* __restrict__ dinv)
{
  __shared__ int stage[6144];
  __shared__ int h[BSZ];
  __shared__ int loff[BSZ];
  __shared__ int cur[BSZ];
  __shared__ int sd[256];
  __shared__ int cbase[NCHUNK];
  __shared__ int ntot;
  const int tid = threadIdx.x;
  const int b = blockIdx.x;
  h[tid] = 0; h[tid + 256] = 0;

  int v = (tid < NCHUNK) ? cnt2[tid * NBUK + b] : 0;
  sd[tid] = v;
  __syncthreads();
  int incl = v;
  for (int o = 1; o < 256; o <<= 1) {
    int add = (tid >= o) ? sd[tid - o] : 0;
    __syncthreads();
    incl += add;
    sd[tid] = incl;
    __syncthreads();
  }
  if (tid < NCHUNK) cbase[tid] = incl - v;
  if (tid == 255) ntot = incl;
  __syncthreads();

  if (tid < NCHUNK) {
    const int* src = ebuf2 + (tid * NBUK + b) * CAPB;
    int base = cbase[tid];
    for (int i = 0; i < v; ++i) stage[base + i] = src[i];
  }
  __syncthreads();
  const int n = ntot;

  for (int i = tid; i < n; i += 256)
    atomicAdd(&h[stage[i] >> 17], 1);
  __syncthreads();

  int r0 = h[2 * tid], r1 = h[2 * tid + 1];
  int p0 = (r0 + 7) & ~7, p1 = (r1 + 7) & ~7;
  int ps = p0 + p1;
  sd[tid] = ps;
  __syncthreads();
  int incl2 = ps;
  for (int o = 1; o < 256; o <<= 1) {
    int add = (tid >= o) ? sd[tid - o] : 0;
    __syncthreads();
    incl2 += add;
    sd[tid] = incl2;
    __syncthreads();
  }
  int ex = incl2 - ps;
  loff[2 * tid] = ex;
  loff[2 * tid + 1] = ex + p0;
  cur[2 * tid] = ex;
  cur[2 * tid + 1] = ex + p0;
  __syncthreads();

  const int node0 = b * BSZ;
  const int cbase2 = b * CAP_C;
#pragma unroll
  for (int t = 0; t < 2; ++t) {
    int j = tid + t * 256;
    int node = node0 + j;
    if (node < NN) {
      int hr = h[j];
      int hp = (hr + 7) & ~7;
      int beg = cbase2 + loff[j];
      rp2[node] = make_int2(beg, beg + hp);
      dinv[node] = rsqrtf((float)hr + 1.0f);
      for (int p = hr; p < hp; ++p) csr[beg + p] = NN;  // pads -> zero row
    }
  }

  for (int i = tid; i < n; i += 256) {
    int w = stage[i];
    int dl = w >> 17;
    int slot = atomicAdd(&cur[dl], 1);
    csr[cbase2 + slot] = w & 0x1FFFF;
  }
}

// ---------------- per-tile layer body (identical math to round-14 k_layer) ----------------
template<bool PSTAGE>
__device__ __forceinline__ void layer_tile(
    int tile, const _Float16* __restrict__ Ain, const int2* __restrict__ rp2,
    const int* __restrict__ csr, const float* __restrict__ bias,
    const float* __restrict__ dinv, _Float16* __restrict__ Aout,
    _Float16* __restrict__ P, _Float16* sW, _Float16* sA, _Float16* sW34)
{
  const int tid = threadIdx.x;
  const int node0 = tile * 128;
  const int l = tid & 63, w = tid >> 6;
  const int grp = l >> 3, c8 = l & 7;

#pragma unroll
  for (int r = 0; r < 2; ++r) {
    int nl = r * 64 + w * 8 + grp;
    int node = node0 + nl;
    float acc[8];
#pragma unroll
    for (int j = 0; j < 8; ++j) acc[j] = 0.f;
    half8 selfv = {};
    if (node < NN) {
      int2 se = rp2[node];
      for (int i = se.x; i < se.y; i += 8) {
        int4 sa = *(const int4*)(csr + i);
        int4 sb = *(const int4*)(csr + i + 4);
        half8 v0 = *(const half8*)(Ain + sa.x * 64 + c8 * 8);
        half8 v1 = *(const half8*)(Ain + sa.y * 64 + c8 * 8);
        half8 v2 = *(const half8*)(Ain + sa.z * 64 + c8 * 8);
        half8 v3 = *(const half8*)(Ain + sa.w * 64 + c8 * 8);
        half8 v4 = *(const half8*)(Ain + sb.x * 64 + c8 * 8);
        half8 v5 = *(const half8*)(Ain + sb.y * 64 + c8 * 8);
        half8 v6 = *(const half8*)(Ain + sb.z * 64 + c8 * 8);
        half8 v7 = *(const half8*)(Ain + sb.w * 64 + c8 * 8);
#pragma unroll
        for (int j = 0; j < 8; ++j)
          acc[j] += (((float)v0[j] + (float)v1[j]) + ((float)v2[j] + (float)v3[j]))
                  + (((float)v4[j] + (float)v5[j]) + ((float)v6[j] + (float)v7[j]));
      }
      selfv = *(const half8*)(Ain + node * 64 + c8 * 8);
    }
    half8 ha;
#pragma unroll
    for (int j = 0; j < 8; ++j) ha[j] = (_Float16)acc[j];
    char* rowp = (char*)sA + nl * 256;
    int swz = (nl & 7) << 4;
    *(half8*)(rowp + ((c8 * 16) ^ swz)) = ha;
    *(half8*)(rowp + ((128 + c8 * 16) ^ swz)) = selfv;
  }
  __syncthreads();

  const int lm = l & 15, lh = l >> 4;
  f32x4 acc[4];
#pragma unroll
  for (int nt = 0; nt < 4; ++nt) acc[nt] = (f32x4){0.f, 0.f, 0.f, 0.f};

  const int arow = w * 16 + lm;
  const int aswz = (arow & 7) << 4;
#pragma unroll
  for (int kb = 0; kb < 4; ++kb) {
    half8 af = *(half8*)((char*)sA + arow * 256 + ((kb * 64 + lh * 16) ^ aswz));
#pragma unroll
    for (int nt = 0; nt < 4; ++nt) {
      int n = nt * 16 + lm;
      half8 bf = *(half8*)((char*)sW + n * 256 + ((kb * 64 + lh * 16) ^ ((n & 7) << 4)));
      acc[nt] = __builtin_amdgcn_mfma_f32_16x16x32_f16(af, bf, acc[nt], 0, 0, 0);
    }
  }

  if (!PSTAGE) {
#pragma unroll
    for (int nt = 0; nt < 4; ++nt) {
      int col = nt * 16 + lm;
      float bv = bias[col];
#pragma unroll
      for (int r2 = 0; r2 < 4; ++r2) {
        int row = node0 + w * 16 + lh * 4 + r2;
        if (row < NN)
          Aout[row * 64 + col] = (_Float16)fmaxf(acc[nt][r2] + bv, 0.f);
      }
    }
  } else {
#pragma unroll
    for (int r2 = 0; r2 < 4; ++r2) {
      int lrow = w * 16 + lh * 4 + r2;
      int grow = node0 + lrow;
      float s = (grow < NN) ? dinv[grow] : 0.f;
      char* rowp = (char*)sA + lrow * 256;
      int swz = (lrow & 7) << 4;
#pragma unroll
      for (int nt = 0; nt < 4; ++nt) {
        int col = nt * 16 + lm;
        float v = fmaxf(acc[nt][r2] + bias[col], 0.f) * s;
        *(_Float16*)(rowp + ((col * 2) ^ swz)) = (_Float16)v;
      }
    }
    f32x4 accP = (f32x4){0.f, 0.f, 0.f, 0.f};
#pragma unroll
    for (int kb = 0; kb < 2; ++kb) {
      half8 af = *(half8*)((char*)sA + arow * 256 + ((kb * 64 + lh * 16) ^ aswz));
      half8 bf = *(half8*)((char*)sW34 + lm * 128 + ((kb * 64 + lh * 16) ^ ((lm & 7) << 4)));
      accP = __builtin_amdgcn_mfma_f32_16x16x32_f16(af, bf, accP, 0, 0, 0);
    }
#pragma unroll
    for (int r2 = 0; r2 < 4; ++r2) {
      int row = node0 + w * 16 + lh * 4 + r2;
      if (row < NN) P[row * 16 + lm] = (_Float16)accP[r2];
    }
  }
  __syncthreads();   // protect sA before next tile's gather writes
}

// ---------------- mega-kernel: layer1 -> sync -> layer2+P -> sync -> head ----------------
__global__ __launch_bounds__(512) void k_gnn(
    const _Float16* __restrict__ xh, _Float16* __restrict__ Ah,
    const int2* __restrict__ rp2, const int* __restrict__ csr,
    const _Float16* __restrict__ W12, const float* __restrict__ b1,
    const float* __restrict__ b2, const float* __restrict__ dinv,
    const _Float16* __restrict__ W34h, _Float16* __restrict__ P,
    const float* __restrict__ cvecg, float* __restrict__ out)
{
  cg::grid_group grid = cg::this_grid();
  __shared__ _Float16 sW[64 * 128];    // 16 KB
  __shared__ _Float16 sA[128 * 128];   // 32 KB
  __shared__ _Float16 sW34[16 * 64];   // 2 KB
  __shared__ float sc[10];

  const int tid = threadIdx.x;

  // ---- phase 1: Ah = relu(concat(agg(xh), xh) @ W1 + b1) ----
  {
    const uint4* g4 = (const uint4*)W12;
#pragma unroll
    for (int i = 0; i < 2; ++i) {
      int c = tid + 512 * i;
      int n = c >> 4, kc = c & 15;
      *(uint4*)((char*)sW + n * 256 + ((kc * 16) ^ ((n & 7) << 4))) = g4[c];
    }
  }
  for (int t = blockIdx.x; t < NTILE; t += gridDim.x)
    layer_tile<false>(t, xh, rp2, csr, b1, nullptr, Ah, nullptr, sW, sA, sW34);

  grid.sync();

  // ---- phase 2: A3 = dinv*relu(concat(agg(Ah),Ah)@W2+b2); P = A3@(W3@Wlin) ----
  {
    const uint4* g4 = (const uint4*)(W12 + 8192);
#pragma unroll
    for (int i = 0; i < 2; ++i) {
      int c = tid + 512 * i;
      int n = c >> 4, kc = c & 15;
      *(uint4*)((char*)sW + n * 256 + ((kc * 16) ^ ((n & 7) << 4))) = g4[c];
    }
    if (tid < 128) {
      int n = tid >> 3, kc = tid & 7;
      uint4 v = ((const uint4*)W34h)[tid];
      *(uint4*)((char*)sW34 + n * 128 + ((kc * 16) ^ ((n & 7) << 4))) = v;
    }
  }
  for (int t = blockIdx.x; t < NTILE; t += gridDim.x)
    layer_tile<true>(t, Ah, rp2, csr, b2, dinv, nullptr, P, sW, sA, sW34);

  grid.sync();

  // ---- phase 3: head. 512 threads -> 256 nodes/tile, 2 lanes/node ----
  if (tid < 10) sc[tid] = cvecg[tid];
  __syncthreads();
  for (int t = blockIdx.x; t < NHTILE; t += gridDim.x) {
    int node = t * 256 + (tid >> 1);
    int half = tid & 1;
    if (node >= NN) continue;
    int2 se = rp2[node];

    float acc[8];
#pragma unroll
    for (int j = 0; j < 8; ++j) acc[j] = 0.f;

    for (int i = se.x; i < se.y; i += 8) {
      int4 sa = *(const int4*)(csr + i);
      int4 sb = *(const int4*)(csr + i + 4);
      half8 v0 = *(const half8*)(P + sa.x * 16 + half * 8);
      half8 v1 = *(const half8*)(P + sa.y * 16 + half * 8);
      half8 v2 = *(const half8*)(P + sa.z * 16 + half * 8);
      half8 v3 = *(const half8*)(P + sa.w * 16 + half * 8);
      half8 v4 = *(const half8*)(P + sb.x * 16 + half * 8);
      half8 v5 = *(const half8*)(P + sb.y * 16 + half * 8);
      half8 v6 = *(const half8*)(P + sb.z * 16 + half * 8);
      half8 v7 = *(const half8*)(P + sb.w * 16 + half * 8);
#pragma unroll
      for (int j = 0; j < 8; ++j)
        acc[j] += (((float)v0[j] + (float)v1[j]) + ((float)v2[j] + (float)v3[j]))
                + (((float)v4[j] + (float)v5[j]) + ((float)v6[j] + (float)v7[j]));
    }
    half8 selfv = *(const half8*)(P + node * 16 + half * 8);
#pragma unroll
    for (int j = 0; j < 8; ++j) acc[j] += (float)selfv[j];

    float dv = dinv[node];
    if (half == 0) {
#pragma unroll
      for (int j = 0; j < 4; ++j) {
        float2 o;
        o.x = fmaf(dv, acc[2 * j], sc[2 * j]);
        o.y = fmaf(dv, acc[2 * j + 1], sc[2 * j + 1]);
        *(float2*)(out + node * 10 + 2 * j) = o;
      }
    } else {
      float2 o;
      o.x = fmaf(dv, acc[0], sc[8]);
      o.y = fmaf(dv, acc[1], sc[9]);
      *(float2*)(out + node * 10 + 8) = o;
    }
  }
}

extern "C" void kernel_launch(void* const* d_in, const int* in_sizes, int n_in,
                              void* d_out, int out_size, void* d_ws, size_t ws_size,
                              hipStream_t stream) {
  const float* x       = (const float*)d_in[0];
  const int*   ei      = (const int*)d_in[1];
  const float* W1_rel  = (const float*)d_in[2];
  const float* b1      = (const float*)d_in[3];
  const float* W1_root = (const float*)d_in[4];
  const float* W2_rel  = (const float*)d_in[5];
  const float* b2      = (const float*)d_in[6];
  const float* W2_root = (const float*)d_in[7];
  const float* W3      = (const float*)d_in[8];
  const float* b3      = (const float*)d_in[9];
  const float* Wlin    = (const float*)d_in[10];
  const float* blin    = (const float*)d_in[11];
  float* out = (float*)d_out;

  char* ws = (char*)d_ws;
  _Float16* xh   = (_Float16*)(ws);               // (NN+1)*64 f16 = 12,800,128 B
  _Float16* Ah   = (_Float16*)(ws + 12800128);    // 12,800,128 B
  float*    dinv = (float*)(ws + 25600256);       //    400,000 B
  int2*     rp2  = (int2*) (ws + 26000256);       //    800,000 B
  int*      csr  = (int*)  (ws + 26800256);       //  5,619,712 B (196*7168*4)
  _Float16* W12  = (_Float16*)(ws + 32419968);    //     32,768 B
  _Float16* W34h = (_Float16*)(ws + 32452736);    //      2,048 B
  float*    cvec = (float*)(ws + 32454784);       //         64 B
  _Float16* P    = (_Float16*)(ws + 32454848);    //  3,200,032 B ((NN+1)*16)
  int*      cnt2 = (int*)  (ws + 35654880);       //    153,664 B (196*196)
  int*      ebuf2= (int*)  (ws + 35808544);       //  9,834,496 B (196*196*64*4)

  dim3 b256(256), b512(512);

  // kernel 1: weights + cvec + dummy rows + x->f16 + atomic-free edge binning
  k_setup<<<3325, b256, 0, stream>>>(W1_rel, W1_root, W2_rel, W2_root, W3, b3, Wlin,
                                     blin, x, ei, W12, W34h, cvec, xh, Ah, P,
                                     cnt2, ebuf2);
  // kernel 2: per-bucket CSR (spans x8-padded, pads -> zero row NN)
  k_csr2<<<NBUK, b256, 0, stream>>>(cnt2, ebuf2, rp2, csr, dinv);

  // kernel 3: cooperative mega-kernel (layer1 -> layer2+P -> head)
  int dev = 0;
  hipGetDevice(&dev);
  int ncu = 256;
  hipDeviceGetAttribute(&ncu, hipDeviceAttributeMultiprocessorCount, dev);
  int maxb = 1;
  hipOccupancyMaxActiveBlocksPerMultiprocessor(&maxb, (const void*)k_gnn, 512, 0);
  if (maxb < 1) maxb = 1;
  int grid = maxb * ncu;
  if (grid > NTILE) grid = NTILE;

  void* args[] = {
    (void*)&xh, (void*)&Ah, (void*)&rp2, (void*)&csr, (void*)&W12,
    (void*)&b1, (void*)&b2, (void*)&dinv, (void*)&W34h, (void*)&P,
    (void*)&cvec, (void*)&out
  };
  hipLaunchCooperativeKernel((const void*)k_gnn, dim3(grid), b512, args, 0, stream);
}

// Round 18
// 115.871 us; speedup vs baseline: 1.6503x; 1.6503x over previous
//
#include <hip/hip_runtime.h>

#define NN 100000
#define NE 800000
#define BSH 9                 // 512 nodes per bucket
#define BSZ (1 << BSH)
#define NBUK ((NN + BSZ - 1) / BSZ)    // 196
#define NCHUNK 196            // edge chunks of 4096
#define CAPB 64               // per-(chunk,bucket) capacity (mean 21, 9 sigma)
#define CAP_C 7168            // csr bucket capacity (x8-padded spans)

typedef _Float16 half8 __attribute__((ext_vector_type(8)));
typedef float f32x4 __attribute__((ext_vector_type(4)));

// ---------------- setup: weights + cvec + dummy rows + x->f16 + edge binning ----------------
__global__ __launch_bounds__(256) void k_setup(
    const float* __restrict__ W1r, const float* __restrict__ W1o,
    const float* __restrict__ W2r, const float* __restrict__ W2o,
    const float* __restrict__ W3, const float* __restrict__ b3,
    const float* __restrict__ Wlin, const float* __restrict__ blin,
    const float* __restrict__ x, const int* __restrict__ ei,
    _Float16* __restrict__ W12, _Float16* __restrict__ W34h,
    float* __restrict__ cvec,
    _Float16* __restrict__ xh, _Float16* __restrict__ Ah, _Float16* __restrict__ P,
    int* __restrict__ cnt2, int* __restrict__ ebuf2)
{
  const int m = blockIdx.x, tid = threadIdx.x;

  if (m >= 3129) {
    __shared__ int curs[256];
    const int c = m - 3129;
    curs[tid] = 0;
    __syncthreads();
    const int e0 = c * 4096;
    int pk[16], bk[16];
#pragma unroll
    for (int i = 0; i < 16; ++i) {
      int e = e0 + i * 256 + tid;
      if (e < NE) {
        int src = ei[e];
        int dst = ei[NE + e];
        bk[i] = dst >> BSH;
        pk[i] = src | ((dst & (BSZ - 1)) << 17);
      } else bk[i] = -1;
    }
#pragma unroll
    for (int i = 0; i < 16; ++i) {
      if (bk[i] >= 0) {
        int slot = atomicAdd(&curs[bk[i]], 1);            // LDS atomic only
        ebuf2[(c * NBUK + bk[i]) * CAPB + slot] = pk[i];
      }
    }
    __syncthreads();
    if (tid < NBUK) cnt2[c * NBUK + tid] = curs[tid];
    return;
  }

  if (m >= 4) {
    int idx = (m - 4) * 256 + tid;              // 0..799999 exact
    const float4* p4 = (const float4*)(x + idx * 8);
    float4 a = p4[0], b = p4[1];
    half8 h;
    h[0] = (_Float16)a.x; h[1] = (_Float16)a.y; h[2] = (_Float16)a.z; h[3] = (_Float16)a.w;
    h[4] = (_Float16)b.x; h[5] = (_Float16)b.y; h[6] = (_Float16)b.z; h[7] = (_Float16)b.w;
    *(half8*)(xh + idx * 8) = h;
    return;
  }

  if (m < 2) {
    const float* Wr = m ? W2r : W1r;
    const float* Wo = m ? W2o : W1o;
    _Float16* dst = W12 + m * 8192;
    for (int idx = tid; idx < 8192; idx += 256) {
      int n = idx >> 7, k = idx & 127;
      float v = (k < 64) ? Wr[k * 64 + n] : Wo[(k - 64) * 64 + n];
      dst[idx] = (_Float16)v;
    }
  } else if (m == 2) {
    // W34h[c][k] = sum_j W3[k][j]*Wlin[j][c], c<10 (0 for c in 10..15)
    for (int idx = tid; idx < 1024; idx += 256) {
      int c = idx >> 6, k = idx & 63;
      float s = 0.f;
      if (c < 10)
        for (int j = 0; j < 64; ++j) s = fmaf(W3[k * 64 + j], Wlin[j * 10 + c], s);
      W34h[idx] = (_Float16)s;
    }
    if (tid < 10) {
      float s = blin[tid];
      for (int j = 0; j < 64; ++j) s = fmaf(b3[j], Wlin[j * 10 + tid], s);
      cvec[tid] = s;
    }
  } else {  // m == 3: dummy zero rows
    if (tid < 64) {
      xh[NN * 64 + tid] = (_Float16)0.f;
      Ah[NN * 64 + tid] = (_Float16)0.f;
    }
    if (tid < 16) P[NN * 16 + tid] = (_Float16)0.f;
  }
}

// ---------------- CSR build: one block per bucket, all state block-local ----------------
__global__ __launch_bounds__(256) void k_csr2(const int* __restrict__ cnt2,
    const int* __restrict__ ebuf2, int2* __restrict__ rp2, int* __restrict__ csr,
    float* __restrict__ dinv)
{
  __shared__ int stage[6144];
  __shared__ int h[BSZ];
  __shared__ int loff[BSZ];
  __shared__ int cur[BSZ];
  __shared__ int sd[256];
  __shared__ int cbase[NCHUNK];
  __shared__ int ntot;
  const int tid = threadIdx.x;
  const int b = blockIdx.x;
  h[tid] = 0; h[tid + 256] = 0;

  int v = (tid < NCHUNK) ? cnt2[tid * NBUK + b] : 0;
  sd[tid] = v;
  __syncthreads();
  int incl = v;
  for (int o = 1; o < 256; o <<= 1) {
    int add = (tid >= o) ? sd[tid - o] : 0;
    __syncthreads();
    incl += add;
    sd[tid] = incl;
    __syncthreads();
  }
  if (tid < NCHUNK) cbase[tid] = incl - v;
  if (tid == 255) ntot = incl;
  __syncthreads();

  if (tid < NCHUNK) {
    const int* src = ebuf2 + (tid * NBUK + b) * CAPB;
    int base = cbase[tid];
    for (int i = 0; i < v; ++i) stage[base + i] = src[i];
  }
  __syncthreads();
  const int n = ntot;

  for (int i = tid; i < n; i += 256)
    atomicAdd(&h[stage[i] >> 17], 1);
  __syncthreads();

  int r0 = h[2 * tid], r1 = h[2 * tid + 1];
  int p0 = (r0 + 7) & ~7, p1 = (r1 + 7) & ~7;
  int ps = p0 + p1;
  sd[tid] = ps;
  __syncthreads();
  int incl2 = ps;
  for (int o = 1; o < 256; o <<= 1) {
    int add = (tid >= o) ? sd[tid - o] : 0;
    __syncthreads();
    incl2 += add;
    sd[tid] = incl2;
    __syncthreads();
  }
  int ex = incl2 - ps;
  loff[2 * tid] = ex;
  loff[2 * tid + 1] = ex + p0;
  cur[2 * tid] = ex;
  cur[2 * tid + 1] = ex + p0;
  __syncthreads();

  const int node0 = b * BSZ;
  const int cbase2 = b * CAP_C;
#pragma unroll
  for (int t = 0; t < 2; ++t) {
    int j = tid + t * 256;
    int node = node0 + j;
    if (node < NN) {
      int hr = h[j];
      int hp = (hr + 7) & ~7;
      int beg = cbase2 + loff[j];
      rp2[node] = make_int2(beg, beg + hp);
      dinv[node] = rsqrtf((float)hr + 1.0f);
      for (int p = hr; p < hp; ++p) csr[beg + p] = NN;  // pads -> zero row
    }
  }

  for (int i = tid; i < n; i += 256) {
    int w = stage[i];
    int dl = w >> 17;
    int slot = atomicAdd(&cur[dl], 1);
    csr[cbase2 + slot] = w & 0x1FFFF;
  }
}

// ---------------- fused layer: gather -> LDS -> K=128 MFMA -> relu(+scale) ----------------
// B-fragments (W12 / W34h) read directly from global (L1-resident, 16B aligned):
// LDS = sA only (32KB) -> 4 blocks/CU instead of 3.
template<bool PSTAGE>
__global__ __launch_bounds__(512) void k_layer(
    const _Float16* __restrict__ Ain, const int2* __restrict__ rp2,
    const int* __restrict__ csr, const _Float16* __restrict__ W12,
    const float* __restrict__ bias, const float* __restrict__ dinv,
    _Float16* __restrict__ Aout, const _Float16* __restrict__ W34h,
    _Float16* __restrict__ P)
{
  __shared__ _Float16 sA[128 * 128];              // 32 KB [node][k] swizzled

  const int tid = threadIdx.x;
  const int node0 = blockIdx.x * 128;
  const int l = tid & 63, w = tid >> 6;

  const int grp = l >> 3, c8 = l & 7;
#pragma unroll
  for (int r = 0; r < 2; ++r) {
    int nl = r * 64 + w * 8 + grp;
    int node = node0 + nl;
    float acc[8];
#pragma unroll
    for (int j = 0; j < 8; ++j) acc[j] = 0.f;
    half8 selfv = {};
    if (node < NN) {
      int2 se = rp2[node];
      for (int i = se.x; i < se.y; i += 8) {
        int4 sa = *(const int4*)(csr + i);
        int4 sb = *(const int4*)(csr + i + 4);
        half8 v0 = *(const half8*)(Ain + sa.x * 64 + c8 * 8);
        half8 v1 = *(const half8*)(Ain + sa.y * 64 + c8 * 8);
        half8 v2 = *(const half8*)(Ain + sa.z * 64 + c8 * 8);
        half8 v3 = *(const half8*)(Ain + sa.w * 64 + c8 * 8);
        half8 v4 = *(const half8*)(Ain + sb.x * 64 + c8 * 8);
        half8 v5 = *(const half8*)(Ain + sb.y * 64 + c8 * 8);
        half8 v6 = *(const half8*)(Ain + sb.z * 64 + c8 * 8);
        half8 v7 = *(const half8*)(Ain + sb.w * 64 + c8 * 8);
#pragma unroll
        for (int j = 0; j < 8; ++j)
          acc[j] += (((float)v0[j] + (float)v1[j]) + ((float)v2[j] + (float)v3[j]))
                  + (((float)v4[j] + (float)v5[j]) + ((float)v6[j] + (float)v7[j]));
      }
      selfv = *(const half8*)(Ain + node * 64 + c8 * 8);
    }
    half8 ha;
#pragma unroll
    for (int j = 0; j < 8; ++j) ha[j] = (_Float16)acc[j];
    char* rowp = (char*)sA + nl * 256;
    int swz = (nl & 7) << 4;
    *(half8*)(rowp + ((c8 * 16) ^ swz)) = ha;
    *(half8*)(rowp + ((128 + c8 * 16) ^ swz)) = selfv;
  }
  __syncthreads();

  const int lm = l & 15, lh = l >> 4;
  f32x4 acc[4];
#pragma unroll
  for (int nt = 0; nt < 4; ++nt) acc[nt] = (f32x4){0.f, 0.f, 0.f, 0.f};

  const int arow = w * 16 + lm;
  const int aswz = (arow & 7) << 4;
#pragma unroll
  for (int kb = 0; kb < 4; ++kb) {
    half8 af = *(half8*)((char*)sA + arow * 256 + ((kb * 64 + lh * 16) ^ aswz));
#pragma unroll
    for (int nt = 0; nt < 4; ++nt) {
      int n = nt * 16 + lm;
      half8 bf = *(const half8*)((const char*)W12 + n * 256 + kb * 64 + lh * 16);
      acc[nt] = __builtin_amdgcn_mfma_f32_16x16x32_f16(af, bf, acc[nt], 0, 0, 0);
    }
  }

  if (!PSTAGE) {
#pragma unroll
    for (int nt = 0; nt < 4; ++nt) {
      int col = nt * 16 + lm;
      float bv = bias[col];
#pragma unroll
      for (int r2 = 0; r2 < 4; ++r2) {
        int row = node0 + w * 16 + lh * 4 + r2;
        if (row < NN)
          Aout[row * 64 + col] = (_Float16)fmaxf(acc[nt][r2] + bv, 0.f);
      }
    }
  } else {
    // A3 = relu(acc+b)*dinv -> own sA band, then mini-MFMA (K=64) -> P.
#pragma unroll
    for (int r2 = 0; r2 < 4; ++r2) {
      int lrow = w * 16 + lh * 4 + r2;
      int grow = node0 + lrow;
      float s = (grow < NN) ? dinv[grow] : 0.f;
      char* rowp = (char*)sA + lrow * 256;
      int swz = (lrow & 7) << 4;
#pragma unroll
      for (int nt = 0; nt < 4; ++nt) {
        int col = nt * 16 + lm;
        float v = fmaxf(acc[nt][r2] + bias[col], 0.f) * s;
        *(_Float16*)(rowp + ((col * 2) ^ swz)) = (_Float16)v;
      }
    }
    f32x4 accP = (f32x4){0.f, 0.f, 0.f, 0.f};
#pragma unroll
    for (int kb = 0; kb < 2; ++kb) {
      half8 af = *(half8*)((char*)sA + arow * 256 + ((kb * 64 + lh * 16) ^ aswz));
      half8 bf = *(const half8*)((const char*)W34h + lm * 128 + kb * 64 + lh * 16);
      accP = __builtin_amdgcn_mfma_f32_16x16x32_f16(af, bf, accP, 0, 0, 0);
    }
#pragma unroll
    for (int r2 = 0; r2 < 4; ++r2) {
      int row = node0 + w * 16 + lh * 4 + r2;
      if (row < NN) P[row * 16 + lm] = (_Float16)accP[r2];
    }
  }
}

// ---------------- head: gather P (32B rows) ----------------
__global__ __launch_bounds__(256) void k_head2(const int2* __restrict__ rp2,
    const int* __restrict__ csr, const _Float16* __restrict__ P,
    const float* __restrict__ dinv, const float* __restrict__ cvecg,
    float* __restrict__ out)
{
  __shared__ float sc[10];
  const int tid = threadIdx.x;
  if (tid < 10) sc[tid] = cvecg[tid];
  __syncthreads();

  const int node = blockIdx.x * 128 + (tid >> 1);
  const int half = tid & 1;
  if (node >= NN) return;
  int2 se = rp2[node];

  float acc[8];
#pragma unroll
  for (int j = 0; j < 8; ++j) acc[j] = 0.f;

  for (int i = se.x; i < se.y; i += 8) {
    int4 sa = *(const int4*)(csr + i);
    int4 sb = *(const int4*)(csr + i + 4);
    half8 v0 = *(const half8*)(P + sa.x * 16 + half * 8);
    half8 v1 = *(const half8*)(P + sa.y * 16 + half * 8);
    half8 v2 = *(const half8*)(P + sa.z * 16 + half * 8);
    half8 v3 = *(const half8*)(P + sa.w * 16 + half * 8);
    half8 v4 = *(const half8*)(P + sb.x * 16 + half * 8);
    half8 v5 = *(const half8*)(P + sb.y * 16 + half * 8);
    half8 v6 = *(const half8*)(P + sb.z * 16 + half * 8);
    half8 v7 = *(const half8*)(P + sb.w * 16 + half * 8);
#pragma unroll
    for (int j = 0; j < 8; ++j)
      acc[j] += (((float)v0[j] + (float)v1[j]) + ((float)v2[j] + (float)v3[j]))
              + (((float)v4[j] + (float)v5[j]) + ((float)v6[j] + (float)v7[j]));
  }
  half8 selfv = *(const half8*)(P + node * 16 + half * 8);
#pragma unroll
  for (int j = 0; j < 8; ++j) acc[j] += (float)selfv[j];

  float dv = dinv[node];
  if (half == 0) {
#pragma unroll
    for (int j = 0; j < 4; ++j) {
      float2 o;
      o.x = fmaf(dv, acc[2 * j], sc[2 * j]);
      o.y = fmaf(dv, acc[2 * j + 1], sc[2 * j + 1]);
      *(float2*)(out + node * 10 + 2 * j) = o;
    }
  } else {
    float2 o;
    o.x = fmaf(dv, acc[0], sc[8]);
    o.y = fmaf(dv, acc[1], sc[9]);
    *(float2*)(out + node * 10 + 8) = o;
  }
}

extern "C" void kernel_launch(void* const* d_in, const int* in_sizes, int n_in,
                              void* d_out, int out_size, void* d_ws, size_t ws_size,
                              hipStream_t stream) {
  const float* x       = (const float*)d_in[0];
  const int*   ei      = (const int*)d_in[1];
  const float* W1_rel  = (const float*)d_in[2];
  const float* b1      = (const float*)d_in[3];
  const float* W1_root = (const float*)d_in[4];
  const float* W2_rel  = (const float*)d_in[5];
  const float* b2      = (const float*)d_in[6];
  const float* W2_root = (const float*)d_in[7];
  const float* W3      = (const float*)d_in[8];
  const float* b3      = (const float*)d_in[9];
  const float* Wlin    = (const float*)d_in[10];
  const float* blin    = (const float*)d_in[11];
  float* out = (float*)d_out;

  char* ws = (char*)d_ws;
  _Float16* xh   = (_Float16*)(ws);               // (NN+1)*64 f16 = 12,800,128 B
  _Float16* Ah   = (_Float16*)(ws + 12800128);    // 12,800,128 B
  float*    dinv = (float*)(ws + 25600256);       //    400,000 B
  int2*     rp2  = (int2*) (ws + 26000256);       //    800,000 B
  int*      csr  = (int*)  (ws + 26800256);       //  5,619,712 B (196*7168*4)
  _Float16* W12  = (_Float16*)(ws + 32419968);    //     32,768 B
  _Float16* W34h = (_Float16*)(ws + 32452736);    //      2,048 B
  float*    cvec = (float*)(ws + 32454784);       //         64 B
  _Float16* P    = (_Float16*)(ws + 32454848);    //  3,200,032 B ((NN+1)*16)
  int*      cnt2 = (int*)  (ws + 35654880);       //    153,664 B (196*196)
  int*      ebuf2= (int*)  (ws + 35808544);       //  9,834,496 B (196*196*64*4)

  dim3 b256(256), b512(512);

  // kernel 1: weights + cvec + dummy rows + x->f16 + atomic-free edge binning
  k_setup<<<3325, b256, 0, stream>>>(W1_rel, W1_root, W2_rel, W2_root, W3, b3, Wlin,
                                     blin, x, ei, W12, W34h, cvec, xh, Ah, P,
                                     cnt2, ebuf2);
  // kernel 2: per-bucket CSR (spans x8-padded, pads -> zero row NN)
  k_csr2<<<NBUK, b256, 0, stream>>>(cnt2, ebuf2, rp2, csr, dinv);

  const int gl = (NN + 127) / 128;   // 782

  // kernel 3: Ah = relu(concat(agg(xh), xh) @ [W1rel;W1root] + b1)
  k_layer<false><<<gl, b512, 0, stream>>>(xh, rp2, csr, W12, b1, nullptr, Ah,
                                          nullptr, nullptr);
  // kernel 4: A3 = dinv*relu(concat(agg(Ah),Ah)@[W2rel;W2root]+b2); P = A3@(W3@Wlin)
  k_layer<true><<<gl, b512, 0, stream>>>(Ah, rp2, csr, W12 + 8192, b2, dinv, nullptr,
                                         W34h, P);
  // kernel 5: out = dinv*(agg(P)+P) + cvec
  k_head2<<<gl, b256, 0, stream>>>(rp2, csr, P, dinv, cvec, out);
}

// Round 19
// 91.799 us; speedup vs baseline: 2.0830x; 1.2622x over previous
//
#include <hip/hip_runtime.h>

#define NN 100000
#define NE 800000
#define BSH 9                 // 512 nodes per bucket
#define BSZ (1 << BSH)
#define NBUK ((NN + BSZ - 1) / BSZ)    // 196
#define NCHUNK 196            // edge chunks of 4096
#define CAPB 64               // per-(chunk,bucket) capacity (mean 21, 9 sigma)
#define CAP_C 7168            // csr bucket capacity (x8-padded spans)

typedef _Float16 half8 __attribute__((ext_vector_type(8)));
typedef float f32x4 __attribute__((ext_vector_type(4)));

// ---------------- kernel 1: edge binning only (atomic-free global) ----------------
__global__ __launch_bounds__(256) void k_bin(const int* __restrict__ ei,
    int* __restrict__ cnt2, int* __restrict__ ebuf2)
{
  __shared__ int curs[256];
  const int c = blockIdx.x, tid = threadIdx.x;
  curs[tid] = 0;
  __syncthreads();
  const int e0 = c * 4096;
  int pk[16], bk[16];
#pragma unroll
  for (int i = 0; i < 16; ++i) {
    int e = e0 + i * 256 + tid;
    if (e < NE) {
      int src = ei[e];
      int dst = ei[NE + e];
      bk[i] = dst >> BSH;
      pk[i] = src | ((dst & (BSZ - 1)) << 17);
    } else bk[i] = -1;
  }
#pragma unroll
  for (int i = 0; i < 16; ++i) {
    if (bk[i] >= 0) {
      int slot = atomicAdd(&curs[bk[i]], 1);            // LDS atomic only
      ebuf2[(c * NBUK + bk[i]) * CAPB + slot] = pk[i];
    }
  }
  __syncthreads();
  if (tid < NBUK) cnt2[c * NBUK + tid] = curs[tid];
}

// ---------------- kernel 2: CSR build (196) + weights (4) + dummy (1) + x16 (3125) ----------------
__global__ __launch_bounds__(256) void k_build(
    const int* __restrict__ cnt2, const int* __restrict__ ebuf2,
    const float* __restrict__ W1r, const float* __restrict__ W1o,
    const float* __restrict__ W2r, const float* __restrict__ W2o,
    const float* __restrict__ W3, const float* __restrict__ b3,
    const float* __restrict__ Wlin, const float* __restrict__ blin,
    const float* __restrict__ x,
    int2* __restrict__ rp2, int* __restrict__ csr, float* __restrict__ dinv,
    _Float16* __restrict__ W12, _Float16* __restrict__ W34h,
    float* __restrict__ cvec,
    _Float16* __restrict__ xh, _Float16* __restrict__ Ah, _Float16* __restrict__ P)
{
  __shared__ int stage[6144];
  __shared__ int h[BSZ];
  __shared__ int loff[BSZ];
  __shared__ int cur[BSZ];
  __shared__ int sd[256];
  __shared__ int cbase[NCHUNK];
  __shared__ int ntot;

  const int m = blockIdx.x, tid = threadIdx.x;

  if (m >= 201) {
    // ---- x -> f16 ----
    int idx = (m - 201) * 256 + tid;            // 0..799999 exact
    const float4* p4 = (const float4*)(x + idx * 8);
    float4 a = p4[0], b = p4[1];
    half8 hh;
    hh[0] = (_Float16)a.x; hh[1] = (_Float16)a.y; hh[2] = (_Float16)a.z; hh[3] = (_Float16)a.w;
    hh[4] = (_Float16)b.x; hh[5] = (_Float16)b.y; hh[6] = (_Float16)b.z; hh[7] = (_Float16)b.w;
    *(half8*)(xh + idx * 8) = hh;
    return;
  }
  if (m >= 196) {
    if (m < 198) {
      int mm = m - 196;
      const float* Wr = mm ? W2r : W1r;
      const float* Wo = mm ? W2o : W1o;
      _Float16* dst = W12 + mm * 8192;
      for (int idx = tid; idx < 8192; idx += 256) {
        int n = idx >> 7, k = idx & 127;
        float v = (k < 64) ? Wr[k * 64 + n] : Wo[(k - 64) * 64 + n];
        dst[idx] = (_Float16)v;
      }
    } else if (m == 198) {
      // W34h[c][k] = sum_j W3[k][j]*Wlin[j][c], c<10 (0 for c in 10..15)
      for (int idx = tid; idx < 1024; idx += 256) {
        int c = idx >> 6, k = idx & 63;
        float s = 0.f;
        if (c < 10)
          for (int j = 0; j < 64; ++j) s = fmaf(W3[k * 64 + j], Wlin[j * 10 + c], s);
        W34h[idx] = (_Float16)s;
      }
      if (tid < 10) {
        float s = blin[tid];
        for (int j = 0; j < 64; ++j) s = fmaf(b3[j], Wlin[j * 10 + tid], s);
        cvec[tid] = s;
      }
    } else {  // m == 199 or 200: dummy zero rows (m==200 spare)
      if (m == 199) {
        if (tid < 64) {
          xh[NN * 64 + tid] = (_Float16)0.f;
          Ah[NN * 64 + tid] = (_Float16)0.f;
        }
        if (tid < 16) P[NN * 16 + tid] = (_Float16)0.f;
      }
    }
    return;
  }

  // ---- CSR build for bucket b = m ----
  const int b = m;
  h[tid] = 0; h[tid + 256] = 0;

  int v = (tid < NCHUNK) ? cnt2[tid * NBUK + b] : 0;
  sd[tid] = v;
  __syncthreads();
  int incl = v;
  for (int o = 1; o < 256; o <<= 1) {
    int add = (tid >= o) ? sd[tid - o] : 0;
    __syncthreads();
    incl += add;
    sd[tid] = incl;
    __syncthreads();
  }
  if (tid < NCHUNK) cbase[tid] = incl - v;
  if (tid == 255) ntot = incl;
  __syncthreads();

  if (tid < NCHUNK) {
    const int* src = ebuf2 + (tid * NBUK + b) * CAPB;
    int base = cbase[tid];
    for (int i = 0; i < v; ++i) stage[base + i] = src[i];
  }
  __syncthreads();
  const int n = ntot;

  for (int i = tid; i < n; i += 256)
    atomicAdd(&h[stage[i] >> 17], 1);
  __syncthreads();

  int r0 = h[2 * tid], r1 = h[2 * tid + 1];
  int p0 = (r0 + 7) & ~7, p1 = (r1 + 7) & ~7;
  int ps = p0 + p1;
  sd[tid] = ps;
  __syncthreads();
  int incl2 = ps;
  for (int o = 1; o < 256; o <<= 1) {
    int add = (tid >= o) ? sd[tid - o] : 0;
    __syncthreads();
    incl2 += add;
    sd[tid] = incl2;
    __syncthreads();
  }
  int ex = incl2 - ps;
  loff[2 * tid] = ex;
  loff[2 * tid + 1] = ex + p0;
  cur[2 * tid] = ex;
  cur[2 * tid + 1] = ex + p0;
  __syncthreads();

  const int node0 = b * BSZ;
  const int cbase2 = b * CAP_C;
#pragma unroll
  for (int t = 0; t < 2; ++t) {
    int j = tid + t * 256;
    int node = node0 + j;
    if (node < NN) {
      int hr = h[j];
      int hp = (hr + 7) & ~7;
      int beg = cbase2 + loff[j];
      rp2[node] = make_int2(beg, beg + hp);
      dinv[node] = rsqrtf((float)hr + 1.0f);
      for (int p = hr; p < hp; ++p) csr[beg + p] = NN;  // pads -> zero row
    }
  }

  for (int i = tid; i < n; i += 256) {
    int w = stage[i];
    int dl = w >> 17;
    int slot = atomicAdd(&cur[dl], 1);
    csr[cbase2 + slot] = w & 0x1FFFF;
  }
}

// ---------------- fused layer: gather -> LDS -> K=128 MFMA -> relu(+scale) ----------------
// (byte-identical to round-14 k_layer)
template<bool PSTAGE>
__global__ __launch_bounds__(512) void k_layer(
    const _Float16* __restrict__ Ain, const int2* __restrict__ rp2,
    const int* __restrict__ csr, const _Float16* __restrict__ W12,
    const float* __restrict__ bias, const float* __restrict__ dinv,
    _Float16* __restrict__ Aout, const _Float16* __restrict__ W34h,
    _Float16* __restrict__ P)
{
  __shared__ _Float16 sW[64 * 128];               // 16 KB [n][k] swizzled
  __shared__ _Float16 sA[128 * 128];              // 32 KB [node][k] swizzled
  __shared__ _Float16 sW34[PSTAGE ? 16 * 64 : 8]; // 2 KB

  const int tid = threadIdx.x;
  const int node0 = blockIdx.x * 128;
  const int l = tid & 63, w = tid >> 6;

  {
    const uint4* g4 = (const uint4*)W12;
#pragma unroll
    for (int i = 0; i < 2; ++i) {
      int c = tid + 512 * i;
      int n = c >> 4, kc = c & 15;
      *(uint4*)((char*)sW + n * 256 + ((kc * 16) ^ ((n & 7) << 4))) = g4[c];
    }
    if (PSTAGE && tid < 128) {
      int n = tid >> 3, kc = tid & 7;             // 16 rows x 8 chunks of 16B
      uint4 v = ((const uint4*)W34h)[tid];
      *(uint4*)((char*)sW34 + n * 128 + ((kc * 16) ^ ((n & 7) << 4))) = v;
    }
  }

  const int grp = l >> 3, c8 = l & 7;
#pragma unroll
  for (int r = 0; r < 2; ++r) {
    int nl = r * 64 + w * 8 + grp;
    int node = node0 + nl;
    float acc[8];
#pragma unroll
    for (int j = 0; j < 8; ++j) acc[j] = 0.f;
    half8 selfv = {};
    if (node < NN) {
      int2 se = rp2[node];
      for (int i = se.x; i < se.y; i += 8) {
        int4 sa = *(const int4*)(csr + i);
        int4 sb = *(const int4*)(csr + i + 4);
        half8 v0 = *(const half8*)(Ain + sa.x * 64 + c8 * 8);
        half8 v1 = *(const half8*)(Ain + sa.y * 64 + c8 * 8);
        half8 v2 = *(const half8*)(Ain + sa.z * 64 + c8 * 8);
        half8 v3 = *(const half8*)(Ain + sa.w * 64 + c8 * 8);
        half8 v4 = *(const half8*)(Ain + sb.x * 64 + c8 * 8);
        half8 v5 = *(const half8*)(Ain + sb.y * 64 + c8 * 8);
        half8 v6 = *(const half8*)(Ain + sb.z * 64 + c8 * 8);
        half8 v7 = *(const half8*)(Ain + sb.w * 64 + c8 * 8);
#pragma unroll
        for (int j = 0; j < 8; ++j)
          acc[j] += (((float)v0[j] + (float)v1[j]) + ((float)v2[j] + (float)v3[j]))
                  + (((float)v4[j] + (float)v5[j]) + ((float)v6[j] + (float)v7[j]));
      }
      selfv = *(const half8*)(Ain + node * 64 + c8 * 8);
    }
    half8 ha;
#pragma unroll
    for (int j = 0; j < 8; ++j) ha[j] = (_Float16)acc[j];
    char* rowp = (char*)sA + nl * 256;
    int swz = (nl & 7) << 4;
    *(half8*)(rowp + ((c8 * 16) ^ swz)) = ha;
    *(half8*)(rowp + ((128 + c8 * 16) ^ swz)) = selfv;
  }
  __syncthreads();

  const int lm = l & 15, lh = l >> 4;
  f32x4 acc[4];
#pragma unroll
  for (int nt = 0; nt < 4; ++nt) acc[nt] = (f32x4){0.f, 0.f, 0.f, 0.f};

  const int arow = w * 16 + lm;
  const int aswz = (arow & 7) << 4;
#pragma unroll
  for (int kb = 0; kb < 4; ++kb) {
    half8 af = *(half8*)((char*)sA + arow * 256 + ((kb * 64 + lh * 16) ^ aswz));
#pragma unroll
    for (int nt = 0; nt < 4; ++nt) {
      int n = nt * 16 + lm;
      half8 bf = *(half8*)((char*)sW + n * 256 + ((kb * 64 + lh * 16) ^ ((n & 7) << 4)));
      acc[nt] = __builtin_amdgcn_mfma_f32_16x16x32_f16(af, bf, acc[nt], 0, 0, 0);
    }
  }

  if (!PSTAGE) {
#pragma unroll
    for (int nt = 0; nt < 4; ++nt) {
      int col = nt * 16 + lm;
      float bv = bias[col];
#pragma unroll
      for (int r2 = 0; r2 < 4; ++r2) {
        int row = node0 + w * 16 + lh * 4 + r2;
        if (row < NN)
          Aout[row * 64 + col] = (_Float16)fmaxf(acc[nt][r2] + bv, 0.f);
      }
    }
  } else {
    // A3 = relu(acc+b)*dinv -> own sA band, then mini-MFMA (K=64) -> P.
#pragma unroll
    for (int r2 = 0; r2 < 4; ++r2) {
      int lrow = w * 16 + lh * 4 + r2;
      int grow = node0 + lrow;
      float s = (grow < NN) ? dinv[grow] : 0.f;
      char* rowp = (char*)sA + lrow * 256;
      int swz = (lrow & 7) << 4;
#pragma unroll
      for (int nt = 0; nt < 4; ++nt) {
        int col = nt * 16 + lm;
        float v = fmaxf(acc[nt][r2] + bias[col], 0.f) * s;
        *(_Float16*)(rowp + ((col * 2) ^ swz)) = (_Float16)v;
      }
    }
    f32x4 accP = (f32x4){0.f, 0.f, 0.f, 0.f};
#pragma unroll
    for (int kb = 0; kb < 2; ++kb) {
      half8 af = *(half8*)((char*)sA + arow * 256 + ((kb * 64 + lh * 16) ^ aswz));
      half8 bf = *(half8*)((char*)sW34 + lm * 128 + ((kb * 64 + lh * 16) ^ ((lm & 7) << 4)));
      accP = __builtin_amdgcn_mfma_f32_16x16x32_f16(af, bf, accP, 0, 0, 0);
    }
#pragma unroll
    for (int r2 = 0; r2 < 4; ++r2) {
      int row = node0 + w * 16 + lh * 4 + r2;
      if (row < NN) P[row * 16 + lm] = (_Float16)accP[r2];
    }
  }
}

// ---------------- head: gather P (32B rows) ----------------
__global__ __launch_bounds__(256) void k_head2(const int2* __restrict__ rp2,
    const int* __restrict__ csr, const _Float16* __restrict__ P,
    const float* __restrict__ dinv, const float* __restrict__ cvecg,
    float* __restrict__ out)
{
  __shared__ float sc[10];
  const int tid = threadIdx.x;
  if (tid < 10) sc[tid] = cvecg[tid];
  __syncthreads();

  const int node = blockIdx.x * 128 + (tid >> 1);
  const int half = tid & 1;
  if (node >= NN) return;
  int2 se = rp2[node];

  float acc[8];
#pragma unroll
  for (int j = 0; j < 8; ++j) acc[j] = 0.f;

  for (int i = se.x; i < se.y; i += 8) {
    int4 sa = *(const int4*)(csr + i);
    int4 sb = *(const int4*)(csr + i + 4);
    half8 v0 = *(const half8*)(P + sa.x * 16 + half * 8);
    half8 v1 = *(const half8*)(P + sa.y * 16 + half * 8);
    half8 v2 = *(const half8*)(P + sa.z * 16 + half * 8);
    half8 v3 = *(const half8*)(P + sa.w * 16 + half * 8);
    half8 v4 = *(const half8*)(P + sb.x * 16 + half * 8);
    half8 v5 = *(const half8*)(P + sb.y * 16 + half * 8);
    half8 v6 = *(const half8*)(P + sb.z * 16 + half * 8);
    half8 v7 = *(const half8*)(P + sb.w * 16 + half * 8);
#pragma unroll
    for (int j = 0; j < 8; ++j)
      acc[j] += (((float)v0[j] + (float)v1[j]) + ((float)v2[j] + (float)v3[j]))
              + (((float)v4[j] + (float)v5[j]) + ((float)v6[j] + (float)v7[j]));
  }
  half8 selfv = *(const half8*)(P + node * 16 + half * 8);
#pragma unroll
  for (int j = 0; j < 8; ++j) acc[j] += (float)selfv[j];

  float dv = dinv[node];
  if (half == 0) {
#pragma unroll
    for (int j = 0; j < 4; ++j) {
      float2 o;
      o.x = fmaf(dv, acc[2 * j], sc[2 * j]);
      o.y = fmaf(dv, acc[2 * j + 1], sc[2 * j + 1]);
      *(float2*)(out + node * 10 + 2 * j) = o;
    }
  } else {
    float2 o;
    o.x = fmaf(dv, acc[0], sc[8]);
    o.y = fmaf(dv, acc[1], sc[9]);
    *(float2*)(out + node * 10 + 8) = o;
  }
}

extern "C" void kernel_launch(void* const* d_in, const int* in_sizes, int n_in,
                              void* d_out, int out_size, void* d_ws, size_t ws_size,
                              hipStream_t stream) {
  const float* x       = (const float*)d_in[0];
  const int*   ei      = (const int*)d_in[1];
  const float* W1_rel  = (const float*)d_in[2];
  const float* b1      = (const float*)d_in[3];
  const float* W1_root = (const float*)d_in[4];
  const float* W2_rel  = (const float*)d_in[5];
  const float* b2      = (const float*)d_in[6];
  const float* W2_root = (const float*)d_in[7];
  const float* W3      = (const float*)d_in[8];
  const float* b3      = (const float*)d_in[9];
  const float* Wlin    = (const float*)d_in[10];
  const float* blin    = (const float*)d_in[11];
  float* out = (float*)d_out;

  char* ws = (char*)d_ws;
  _Float16* xh   = (_Float16*)(ws);               // (NN+1)*64 f16 = 12,800,128 B
  _Float16* Ah   = (_Float16*)(ws + 12800128);    // 12,800,128 B
  float*    dinv = (float*)(ws + 25600256);       //    400,000 B
  int2*     rp2  = (int2*) (ws + 26000256);       //    800,000 B
  int*      csr  = (int*)  (ws + 26800256);       //  5,619,712 B (196*7168*4)
  _Float16* W12  = (_Float16*)(ws + 32419968);    //     32,768 B
  _Float16* W34h = (_Float16*)(ws + 32452736);    //      2,048 B
  float*    cvec = (float*)(ws + 32454784);       //         64 B
  _Float16* P    = (_Float16*)(ws + 32454848);    //  3,200,032 B ((NN+1)*16)
  int*      cnt2 = (int*)  (ws + 35654880);       //    153,664 B (196*196)
  int*      ebuf2= (int*)  (ws + 35808544);       //  9,834,496 B (196*196*64*4)

  dim3 b256(256), b512(512);

  // kernel 1: edge binning only
  k_bin<<<NCHUNK, b256, 0, stream>>>(ei, cnt2, ebuf2);
  // kernel 2: CSR build (depends on binning) co-runs with weights + x16 (independent)
  k_build<<<201 + 3125, b256, 0, stream>>>(cnt2, ebuf2, W1_rel, W1_root, W2_rel,
                                           W2_root, W3, b3, Wlin, blin, x,
                                           rp2, csr, dinv, W12, W34h, cvec,
                                           xh, Ah, P);

  const int gl = (NN + 127) / 128;   // 782

  // kernel 3: Ah = relu(concat(agg(xh), xh) @ [W1rel;W1root] + b1)
  k_layer<false><<<gl, b512, 0, stream>>>(xh, rp2, csr, W12, b1, nullptr, Ah,
                                          nullptr, nullptr);
  // kernel 4: A3 = dinv*relu(concat(agg(Ah),Ah)@[W2rel;W2root]+b2); P = A3@(W3@Wlin)
  k_layer<true><<<gl, b512, 0, stream>>>(Ah, rp2, csr, W12 + 8192, b2, dinv, nullptr,
                                         W34h, P);
  // kernel 5: out = dinv*(agg(P)+P) + cvec
  k_head2<<<gl, b256, 0, stream>>>(rp2, csr, P, dinv, cvec, out);
}